// Round 1
// 206.246 us; speedup vs baseline: 1.0260x; 1.0260x over previous
//
#include <hip/hip_runtime.h>

// DynamicRouting: grouped 1x1 conv (einsum bgihw,gfi->bgfhw) + 3-iter routing.
// B=16, G=8, FI=FO=64, HW=4096. Fully fused: con never touches HBM.
//
// R5: decouple weight loads from the x-prefetch vmcnt FIFO. R4 issued the 16
// per-group weight-fragment vmem loads AFTER the x prefetch and consumed them
// immediately -> every XGRP drained ALL outstanding x loads (FIFO vmcnt),
// collapsing in-flight HBM bytes to ~0 per group (~45% of peak BW). R5 stages
// each group's 16 KB weight tile into LDS once per block via global_load_lds
// (linear dest == wbuf's fragment order), double-buffered, consumed via
// ds_read_b128 (lgkmcnt - separate counter). Hand-counted s_waitcnt
// vmcnt(36/20/0) + raw s_barrier (never vmcnt(0) mid-loop) keep the x stream
// 2 groups (32 loads, 8 KB/wave) deep at all times. Weight L2 traffic/block
// drops 4x (512->128 KB). MFMA math + routing epilogue identical to R4
// (passed, absmax 0.125).

typedef __attribute__((ext_vector_type(8))) _Float16 half8;
typedef __attribute__((ext_vector_type(4))) float f32x4;

#define NG   8
#define NFI  64
#define NFO  64
#define HW   4096

__device__ __forceinline__ float sigmoidf_fast(float v) {
    float e = __builtin_amdgcn_exp2f(-1.44269504088896f * v);
    return __builtin_amdgcn_rcpf(1.0f + e);
}

// ---- kernel 1: repack weights fp32 -> fragment-ordered (h,l) fp16 ----
// wbuf[((g*4+t)*4+c)*512 + lane*8 + j]:
//   c=0: h, k=q*8+j   c=1: h, k=32+q*8+j   c=2: l, k=q*8+j   c=3: l, k=32+q*8+j
__global__ __launch_bounds__(256)
void wconv_kernel(const float* __restrict__ w, _Float16* __restrict__ wbuf) {
    int V = blockIdx.x * 256 + threadIdx.x;   // 0..8191 fragments
    int g    = V >> 10;
    int t    = (V >> 8) & 3;
    int c    = (V >> 6) & 3;
    int lane = V & 63;
    int pl = lane & 15, q = lane >> 4;
    const float* src = w + g * (NFO * NFI) + (t * 16 + pl) * NFI + (c & 1) * 32 + q * 8;
    half8 o;
    #pragma unroll
    for (int j = 0; j < 8; ++j) {
        float f = src[j];
        _Float16 h = (_Float16)f;
        o[j] = (c >> 1) ? (_Float16)(f - (float)h) : h;
    }
    *(half8*)(wbuf + (size_t)V * 8) = o;
}

// ---- kernel 2: fused conv + routing, LDS-staged weights, depth-2 x pipeline ----
__global__ __launch_bounds__(256, 2)
void routing_kernel(const float* __restrict__ x,
                    const _Float16* __restrict__ wbuf,
                    const float* __restrict__ bias,
                    float* __restrict__ out) {
    const int tid  = threadIdx.x;
    const int b    = blockIdx.x >> 6;          // batch
    const int p0   = (blockIdx.x & 63) << 6;   // pixel tile base
    const int lane = tid & 63;
    const int wv   = tid >> 6;                 // wave -> 16-px slice
    const int pl   = lane & 15;                // MFMA n-lane (pixel)
    const int q    = lane >> 4;                // k-octet select / C row group
    const int pw   = wv * 16 + pl;             // pixel within tile

    // double-buffered per-group weight tiles, linear copy of wbuf[g] (16 KB each)
    __shared__ _Float16 wlds[2][16 * 512];

    const float* xg = x + (size_t)b * (NG * NFI) * HW + p0 + pw;

    f32x4 acc[NG][4];
    #pragma unroll
    for (int g = 0; g < NG; ++g)
        #pragma unroll
        for (int t = 0; t < 4; ++t)
            acc[g][t] = (f32x4){0.f, 0.f, 0.f, 0.f};

    // compiler barrier: pins vmem issue (FIFO) order across pipeline stages
#define CB   asm volatile("" ::: "memory")
#define BAR  __builtin_amdgcn_s_barrier()
#define SB0  __builtin_amdgcn_sched_barrier(0)
#define WAITV(N) asm volatile("s_waitcnt vmcnt(" #N ")" ::: "memory")

    // stage group G's 16 KB weight tile into wlds[BUF]; wave wv moves chunks
    // [wv*4, wv*4+4) of 1 KB each. global_load_lds: per-lane global src,
    // LDS dest = uniform base + lane*16 -> exactly wbuf's fragment order.
#define WSTAGE(G, BUF)                                                        \
    {                                                                         \
        const _Float16* ws_ = wbuf + (size_t)(G) * 8192 + (wv * 4) * 512 + lane * 8; \
        _Float16* wd_ = &wlds[BUF][0] + (wv * 4) * 512;                       \
        __builtin_amdgcn_global_load_lds(                                     \
            (const __attribute__((address_space(1))) void*)(ws_),             \
            (__attribute__((address_space(3))) void*)(wd_), 16, 0, 0);        \
        __builtin_amdgcn_global_load_lds(                                     \
            (const __attribute__((address_space(1))) void*)(ws_ + 512),       \
            (__attribute__((address_space(3))) void*)(wd_ + 512), 16, 0, 0);  \
        __builtin_amdgcn_global_load_lds(                                     \
            (const __attribute__((address_space(1))) void*)(ws_ + 1024),      \
            (__attribute__((address_space(3))) void*)(wd_ + 1024), 16, 0, 0); \
        __builtin_amdgcn_global_load_lds(                                     \
            (const __attribute__((address_space(1))) void*)(ws_ + 1536),      \
            (__attribute__((address_space(3))) void*)(wd_ + 1536), 16, 0, 0); \
    }

    // explicitly named scalar buffers — no runtime-indexed private arrays
#define XDECL(NM) float NM##0, NM##1, NM##2, NM##3, NM##4, NM##5, NM##6, NM##7, \
                        NM##8, NM##9, NM##10, NM##11, NM##12, NM##13, NM##14, NM##15;
#define XLOAD(G, NM)                                                         \
    {                                                                        \
        const float* p_ = xg + (size_t)((G) * 64 + q * 8) * HW;              \
        NM##0 = p_[(size_t)0 * HW];  NM##1 = p_[(size_t)1 * HW];             \
        NM##2 = p_[(size_t)2 * HW];  NM##3 = p_[(size_t)3 * HW];             \
        NM##4 = p_[(size_t)4 * HW];  NM##5 = p_[(size_t)5 * HW];             \
        NM##6 = p_[(size_t)6 * HW];  NM##7 = p_[(size_t)7 * HW];             \
        const float* p2_ = p_ + (size_t)32 * HW;                             \
        NM##8  = p2_[(size_t)0 * HW]; NM##9  = p2_[(size_t)1 * HW];          \
        NM##10 = p2_[(size_t)2 * HW]; NM##11 = p2_[(size_t)3 * HW];          \
        NM##12 = p2_[(size_t)4 * HW]; NM##13 = p2_[(size_t)5 * HW];          \
        NM##14 = p2_[(size_t)6 * HW]; NM##15 = p2_[(size_t)7 * HW];          \
    }
    // consume x regs (compiler-tracked waits) + weight tile from LDS (lgkmcnt)
#define XGRP(G, NM, BUF)                                                     \
    {                                                                        \
        half8 b0, b1;                                                        \
        b0[0] = (_Float16)NM##0;  b0[1] = (_Float16)NM##1;                   \
        b0[2] = (_Float16)NM##2;  b0[3] = (_Float16)NM##3;                   \
        b0[4] = (_Float16)NM##4;  b0[5] = (_Float16)NM##5;                   \
        b0[6] = (_Float16)NM##6;  b0[7] = (_Float16)NM##7;                   \
        b1[0] = (_Float16)NM##8;  b1[1] = (_Float16)NM##9;                   \
        b1[2] = (_Float16)NM##10; b1[3] = (_Float16)NM##11;                  \
        b1[4] = (_Float16)NM##12; b1[5] = (_Float16)NM##13;                  \
        b1[6] = (_Float16)NM##14; b1[7] = (_Float16)NM##15;                  \
        const _Float16* wg_ = &wlds[BUF][0] + lane * 8;                      \
        _Pragma("unroll")                                                    \
        for (int t = 0; t < 4; ++t) {                                        \
            const _Float16* wp_ = wg_ + (size_t)t * 2048;                    \
            half8 a0h = *(const half8*)(wp_);                                \
            half8 a1h = *(const half8*)(wp_ + 512);                          \
            half8 a0l = *(const half8*)(wp_ + 1024);                         \
            half8 a1l = *(const half8*)(wp_ + 1536);                         \
            acc[G][t] = __builtin_amdgcn_mfma_f32_16x16x32_f16(a0h, b0, acc[G][t], 0, 0, 0); \
            acc[G][t] = __builtin_amdgcn_mfma_f32_16x16x32_f16(a1h, b1, acc[G][t], 0, 0, 0); \
            acc[G][t] = __builtin_amdgcn_mfma_f32_16x16x32_f16(a0l, b0, acc[G][t], 0, 0, 0); \
            acc[G][t] = __builtin_amdgcn_mfma_f32_16x16x32_f16(a1l, b1, acc[G][t], 0, 0, 0); \
        }                                                                    \
    }

    XDECL(X0) XDECL(X1) XDECL(X2)

    // Prologue FIFO: W0(4) X0(16) W1(4) X1(16)
    WSTAGE(0, 0); CB;
    XLOAD(0, X0); CB;
    WSTAGE(1, 1); CB;
    XLOAD(1, X1); CB;

    // Steady step g: [XLOAD(g+2)] [vmcnt: retire through W(g) -> leaves
    // X(g+1)+W(g+1)+X(g+2) = 36 in flight] [barrier: tile g visible]
    // [compute g] [barrier: tile g free] [stage W(g+2) into freed buffer].
    XLOAD(2, X2); WAITV(36); BAR; SB0; XGRP(0, X0, 0); BAR; WSTAGE(2, 0); CB;
    XLOAD(3, X0); WAITV(36); BAR; SB0; XGRP(1, X1, 1); BAR; WSTAGE(3, 1); CB;
    XLOAD(4, X1); WAITV(36); BAR; SB0; XGRP(2, X2, 0); BAR; WSTAGE(4, 0); CB;
    XLOAD(5, X2); WAITV(36); BAR; SB0; XGRP(3, X0, 1); BAR; WSTAGE(5, 1); CB;
    XLOAD(6, X0); WAITV(36); BAR; SB0; XGRP(4, X1, 0); BAR; WSTAGE(6, 0); CB;
    XLOAD(7, X1); WAITV(36); BAR; SB0; XGRP(5, X2, 1); BAR; WSTAGE(7, 1); CB;
                  WAITV(20); BAR; SB0; XGRP(6, X0, 0);
                  WAITV(0);  BAR; SB0; XGRP(7, X1, 1);

#undef XDECL
#undef XLOAD
#undef XGRP
#undef WSTAGE
#undef CB
#undef BAR
#undef SB0
#undef WAITV

    // ---- routing (all fp32, per pixel), f = t*16 + q*4 + r ----
    // iter 0: v0[f] = 0.5*sum_g con ; beta1[g] = sum_f v0*con
    float v0[4][4];
    #pragma unroll
    for (int t = 0; t < 4; ++t)
        #pragma unroll
        for (int r = 0; r < 4; ++r) {
            float s = 0.f;
            #pragma unroll
            for (int g = 0; g < NG; ++g) s += acc[g][t][r];
            v0[t][r] = 0.5f * s;
        }

    float beta[NG], alpha[NG];
    #pragma unroll
    for (int g = 0; g < NG; ++g) {
        float s = 0.f;
        #pragma unroll
        for (int t = 0; t < 4; ++t)
            #pragma unroll
            for (int r = 0; r < 4; ++r)
                s += v0[t][r] * acc[g][t][r];
        s += __shfl_xor(s, 16);   // close f-sum across the 4 q-lanes
        s += __shfl_xor(s, 32);
        beta[g]  = s;
        alpha[g] = sigmoidf_fast(s);
    }

    // iter 1: v1[f] = sum_g alpha*con ; beta2 = beta1 + sum_f v1*con
    #pragma unroll
    for (int t = 0; t < 4; ++t)
        #pragma unroll
        for (int r = 0; r < 4; ++r) {
            float s = 0.f;
            #pragma unroll
            for (int g = 0; g < NG; ++g) s += alpha[g] * acc[g][t][r];
            v0[t][r] = s;  // reuse as v1
        }
    #pragma unroll
    for (int g = 0; g < NG; ++g) {
        float s = 0.f;
        #pragma unroll
        for (int t = 0; t < 4; ++t)
            #pragma unroll
            for (int r = 0; r < 4; ++r)
                s += v0[t][r] * acc[g][t][r];
        s += __shfl_xor(s, 16);
        s += __shfl_xor(s, 32);
        beta[g] += s;
        alpha[g] = sigmoidf_fast(beta[g]);
    }

    // iter 2: out[f] = sum_g alpha2*con + bias[f]
    #pragma unroll
    for (int t = 0; t < 4; ++t)
        #pragma unroll
        for (int r = 0; r < 4; ++r) {
            int f = t * 16 + q * 4 + r;
            float s = bias[f];
            #pragma unroll
            for (int g = 0; g < NG; ++g) s += alpha[g] * acc[g][t][r];
            out[((size_t)(b * NFO + f)) * HW + p0 + pw] = s;
        }
}

extern "C" void kernel_launch(void* const* d_in, const int* in_sizes, int n_in,
                              void* d_out, int out_size, void* d_ws, size_t ws_size,
                              hipStream_t stream) {
    const float* x    = (const float*)d_in[0];
    const float* w    = (const float*)d_in[1];
    const float* bias = (const float*)d_in[2];
    float* out = (float*)d_out;
    _Float16* wbuf = (_Float16*)d_ws;   // 128 KiB fragment-ordered (h,l) weights

    wconv_kernel<<<32, 256, 0, stream>>>(w, wbuf);
    routing_kernel<<<1024, 256, 0, stream>>>(x, wbuf, bias, out);
}

// Round 2
// 201.376 us; speedup vs baseline: 1.0509x; 1.0242x over previous
//
#include <hip/hip_runtime.h>

// DynamicRouting: grouped 1x1 conv (einsum bgihw,gfi->bgfhw) + 3-iter routing.
// B=16, G=8, FI=FO=64, HW=4096. Fully fused: con never touches HBM.
//
// R6: x goes through LDS via global_load_lds width=16 (1 KB/instruction,
// 256 B contiguous per channel row = 4 full cache lines per burst) instead of
// R5's 16 scalar dword loads per group (64 B granules, 4x the request count,
// poor DRAM page locality -> ~60% of achievable BW). W and X share one uniform
// 8-instr/group vmem FIFO, depth-2 double-buffered, counted s_waitcnt vmcnt(8)
// (never 0 mid-loop) + raw s_barrier. B-frags rebuilt from LDS with a rotation
// swizzle slot=(p + 8*(ch>>3))&63 applied on the GLOBAL source address (LDS
// dest stays linear, as global_load_lds requires); read banks = (pl+8q+16wv)
// mod 32 -> 2 lanes/bank = conflict-free. MFMA sequence + routing epilogue are
// bit-identical to R4/R5 (passed, absmax 0.125).

typedef __attribute__((ext_vector_type(8))) _Float16 half8;
typedef __attribute__((ext_vector_type(4))) float f32x4;

#define NG   8
#define NFI  64
#define NFO  64
#define HW   4096

__device__ __forceinline__ float sigmoidf_fast(float v) {
    float e = __builtin_amdgcn_exp2f(-1.44269504088896f * v);
    return __builtin_amdgcn_rcpf(1.0f + e);
}

// ---- kernel 1: repack weights fp32 -> fragment-ordered (h,l) fp16 ----
// wbuf[((g*4+t)*4+c)*512 + lane*8 + j]:
//   c=0: h, k=q*8+j   c=1: h, k=32+q*8+j   c=2: l, k=q*8+j   c=3: l, k=32+q*8+j
__global__ __launch_bounds__(256)
void wconv_kernel(const float* __restrict__ w, _Float16* __restrict__ wbuf) {
    int V = blockIdx.x * 256 + threadIdx.x;   // 0..8191 fragments
    int g    = V >> 10;
    int t    = (V >> 8) & 3;
    int c    = (V >> 6) & 3;
    int lane = V & 63;
    int pl = lane & 15, q = lane >> 4;
    const float* src = w + g * (NFO * NFI) + (t * 16 + pl) * NFI + (c & 1) * 32 + q * 8;
    half8 o;
    #pragma unroll
    for (int j = 0; j < 8; ++j) {
        float f = src[j];
        _Float16 h = (_Float16)f;
        o[j] = (c >> 1) ? (_Float16)(f - (float)h) : h;
    }
    *(half8*)(wbuf + (size_t)V * 8) = o;
}

// ---- kernel 2: fused conv + routing, LDS-staged x AND w, depth-2 pipeline ----
__global__ __launch_bounds__(256, 2)
void routing_kernel(const float* __restrict__ x,
                    const _Float16* __restrict__ wbuf,
                    const float* __restrict__ bias,
                    float* __restrict__ out) {
    const int tid  = threadIdx.x;
    const int b    = blockIdx.x >> 6;          // batch
    const int p0   = (blockIdx.x & 63) << 6;   // pixel tile base
    const int lane = tid & 63;
    const int wv   = tid >> 6;                 // wave -> 16-px slice
    const int pl   = lane & 15;                // MFMA n-lane (pixel)
    const int q    = lane >> 4;                // k-octet select / C row group
    const int pw   = wv * 16 + pl;             // pixel within tile

    // double-buffered tiles: x = 64ch x 64px fp32 (16 KB), w = 16 KB fp16
    __shared__ float    xlds[2][64 * 64];
    __shared__ _Float16 wlds[2][16 * 512];

    const float* xbase = x + (size_t)b * (NG * NFI) * HW;

    // per-lane X-stage source pointers. Stage instr c: wave writes LDS floats
    // [(wv*16 + c*4)*64, +256) linearly (lane i -> +i*4 floats). Lane covers
    // ch = wv*16 + c*4 + (lane>>4), slots pl*4..pl*4+3. Rotation swizzle:
    // LDS[ch*64 + s] holds pixel p = (s - 8*(ch>>3)) & 63, so the global
    // source is pre-rotated; runs of 4 slots map to contiguous 4-px runs.
#define MKXS(c) \
    const int   ch##c = wv * 16 + (c) * 4 + q; \
    const float* xs##c = xbase + (size_t)ch##c * HW + p0 + ((pl * 4 - 8 * (ch##c >> 3)) & 63);
    MKXS(0) MKXS(1) MKXS(2) MKXS(3)
#undef MKXS

    // b-frag read bases (floats, within a 16 KB x tile):
    //   b0 row ch=q*8+j  : rot=8q    -> slot=(pw+8q)&63,    + j*64
    //   b1 row ch=32+q*8+j: rot=32+8q -> slot=(pw+8q+32)&63, + j*64
    // bank = (pl + 8q + 16wv) mod 32 -> exactly 2 lanes/bank (free).
    const int rb0 = q * 512 + ((pw + 8 * q) & 63);
    const int rb1 = 2048 + q * 512 + ((pw + 8 * q + 32) & 63);

    f32x4 acc[NG][4];
    #pragma unroll
    for (int g = 0; g < NG; ++g)
        #pragma unroll
        for (int t = 0; t < 4; ++t)
            acc[g][t] = (f32x4){0.f, 0.f, 0.f, 0.f};

#define CB   asm volatile("" ::: "memory")
#define BAR  __builtin_amdgcn_s_barrier()
#define SB0  __builtin_amdgcn_sched_barrier(0)
#define WAITV(N) asm volatile("s_waitcnt vmcnt(" #N ")" ::: "memory")

    // stage group G's 16 KB weight tile (linear, fragment order)
#define WSTAGE(G, BUF)                                                        \
    {                                                                         \
        const _Float16* ws_ = wbuf + (size_t)(G) * 8192 + (wv * 4) * 512 + lane * 8; \
        _Float16* wd_ = &wlds[BUF][0] + (wv * 4) * 512;                       \
        __builtin_amdgcn_global_load_lds(                                     \
            (const __attribute__((address_space(1))) void*)(ws_),             \
            (__attribute__((address_space(3))) void*)(wd_), 16, 0, 0);        \
        __builtin_amdgcn_global_load_lds(                                     \
            (const __attribute__((address_space(1))) void*)(ws_ + 512),       \
            (__attribute__((address_space(3))) void*)(wd_ + 512), 16, 0, 0);  \
        __builtin_amdgcn_global_load_lds(                                     \
            (const __attribute__((address_space(1))) void*)(ws_ + 1024),      \
            (__attribute__((address_space(3))) void*)(wd_ + 1024), 16, 0, 0); \
        __builtin_amdgcn_global_load_lds(                                     \
            (const __attribute__((address_space(1))) void*)(ws_ + 1536),      \
            (__attribute__((address_space(3))) void*)(wd_ + 1536), 16, 0, 0); \
    }

    // stage group G's 16 KB x tile: 4 x 1 KB instructions per wave
#define XSTAGE(G, BUF)                                                        \
    {                                                                         \
        const size_t go_ = (size_t)(G) * 64 * HW;                             \
        float* xd_ = &xlds[BUF][0] + (wv * 16) * 64;                          \
        __builtin_amdgcn_global_load_lds(                                     \
            (const __attribute__((address_space(1))) void*)(xs0 + go_),       \
            (__attribute__((address_space(3))) void*)(xd_), 16, 0, 0);        \
        __builtin_amdgcn_global_load_lds(                                     \
            (const __attribute__((address_space(1))) void*)(xs1 + go_),       \
            (__attribute__((address_space(3))) void*)(xd_ + 256), 16, 0, 0);  \
        __builtin_amdgcn_global_load_lds(                                     \
            (const __attribute__((address_space(1))) void*)(xs2 + go_),       \
            (__attribute__((address_space(3))) void*)(xd_ + 512), 16, 0, 0);  \
        __builtin_amdgcn_global_load_lds(                                     \
            (const __attribute__((address_space(1))) void*)(xs3 + go_),       \
            (__attribute__((address_space(3))) void*)(xd_ + 768), 16, 0, 0);  \
    }

    // consume group G from buffer BUF: b-frags from xlds, a-frags from wlds
#define XGRP(G, BUF)                                                         \
    {                                                                        \
        const float* xr0_ = &xlds[BUF][0] + rb0;                             \
        const float* xr1_ = &xlds[BUF][0] + rb1;                             \
        half8 b0, b1;                                                        \
        b0[0] = (_Float16)xr0_[0 * 64]; b0[1] = (_Float16)xr0_[1 * 64];      \
        b0[2] = (_Float16)xr0_[2 * 64]; b0[3] = (_Float16)xr0_[3 * 64];      \
        b0[4] = (_Float16)xr0_[4 * 64]; b0[5] = (_Float16)xr0_[5 * 64];      \
        b0[6] = (_Float16)xr0_[6 * 64]; b0[7] = (_Float16)xr0_[7 * 64];      \
        b1[0] = (_Float16)xr1_[0 * 64]; b1[1] = (_Float16)xr1_[1 * 64];      \
        b1[2] = (_Float16)xr1_[2 * 64]; b1[3] = (_Float16)xr1_[3 * 64];      \
        b1[4] = (_Float16)xr1_[4 * 64]; b1[5] = (_Float16)xr1_[5 * 64];      \
        b1[6] = (_Float16)xr1_[6 * 64]; b1[7] = (_Float16)xr1_[7 * 64];      \
        const _Float16* wg_ = &wlds[BUF][0] + lane * 8;                      \
        _Pragma("unroll")                                                    \
        for (int t = 0; t < 4; ++t) {                                        \
            const _Float16* wp_ = wg_ + (size_t)t * 2048;                    \
            half8 a0h = *(const half8*)(wp_);                                \
            half8 a1h = *(const half8*)(wp_ + 512);                          \
            half8 a0l = *(const half8*)(wp_ + 1024);                         \
            half8 a1l = *(const half8*)(wp_ + 1536);                         \
            acc[G][t] = __builtin_amdgcn_mfma_f32_16x16x32_f16(a0h, b0, acc[G][t], 0, 0, 0); \
            acc[G][t] = __builtin_amdgcn_mfma_f32_16x16x32_f16(a1h, b1, acc[G][t], 0, 0, 0); \
            acc[G][t] = __builtin_amdgcn_mfma_f32_16x16x32_f16(a0l, b0, acc[G][t], 0, 0, 0); \
            acc[G][t] = __builtin_amdgcn_mfma_f32_16x16x32_f16(a1l, b1, acc[G][t], 0, 0, 0); \
        }                                                                    \
    }

    // Prologue: two stage-pairs in flight (8 vmem instrs each)
    WSTAGE(0, 0); XSTAGE(0, 0); CB;
    WSTAGE(1, 1); XSTAGE(1, 1); CB;

    // Steady step g: [vmcnt(8): retire stage(g), keep stage(g+1) in flight]
    // [barrier: tile g visible to all waves] [compute g] [barrier: tile g
    // free] [stage g+2 into freed buffer]. 16 outstanding at every wait.
    WAITV(8); BAR; SB0; XGRP(0, 0); BAR; WSTAGE(2, 0); XSTAGE(2, 0); CB;
    WAITV(8); BAR; SB0; XGRP(1, 1); BAR; WSTAGE(3, 1); XSTAGE(3, 1); CB;
    WAITV(8); BAR; SB0; XGRP(2, 0); BAR; WSTAGE(4, 0); XSTAGE(4, 0); CB;
    WAITV(8); BAR; SB0; XGRP(3, 1); BAR; WSTAGE(5, 1); XSTAGE(5, 1); CB;
    WAITV(8); BAR; SB0; XGRP(4, 0); BAR; WSTAGE(6, 0); XSTAGE(6, 0); CB;
    WAITV(8); BAR; SB0; XGRP(5, 1); BAR; WSTAGE(7, 1); XSTAGE(7, 1); CB;
    WAITV(8); BAR; SB0; XGRP(6, 0); BAR;
    WAITV(0); BAR; SB0; XGRP(7, 1);

#undef XGRP
#undef XSTAGE
#undef WSTAGE
#undef CB
#undef BAR
#undef SB0
#undef WAITV

    // ---- routing (all fp32, per pixel), f = t*16 + q*4 + r ----
    // iter 0: v0[f] = 0.5*sum_g con ; beta1[g] = sum_f v0*con
    float v0[4][4];
    #pragma unroll
    for (int t = 0; t < 4; ++t)
        #pragma unroll
        for (int r = 0; r < 4; ++r) {
            float s = 0.f;
            #pragma unroll
            for (int g = 0; g < NG; ++g) s += acc[g][t][r];
            v0[t][r] = 0.5f * s;
        }

    float beta[NG], alpha[NG];
    #pragma unroll
    for (int g = 0; g < NG; ++g) {
        float s = 0.f;
        #pragma unroll
        for (int t = 0; t < 4; ++t)
            #pragma unroll
            for (int r = 0; r < 4; ++r)
                s += v0[t][r] * acc[g][t][r];
        s += __shfl_xor(s, 16);   // close f-sum across the 4 q-lanes
        s += __shfl_xor(s, 32);
        beta[g]  = s;
        alpha[g] = sigmoidf_fast(s);
    }

    // iter 1: v1[f] = sum_g alpha*con ; beta2 = beta1 + sum_f v1*con
    #pragma unroll
    for (int t = 0; t < 4; ++t)
        #pragma unroll
        for (int r = 0; r < 4; ++r) {
            float s = 0.f;
            #pragma unroll
            for (int g = 0; g < NG; ++g) s += alpha[g] * acc[g][t][r];
            v0[t][r] = s;  // reuse as v1
        }
    #pragma unroll
    for (int g = 0; g < NG; ++g) {
        float s = 0.f;
        #pragma unroll
        for (int t = 0; t < 4; ++t)
            #pragma unroll
            for (int r = 0; r < 4; ++r)
                s += v0[t][r] * acc[g][t][r];
        s += __shfl_xor(s, 16);
        s += __shfl_xor(s, 32);
        beta[g] += s;
        alpha[g] = sigmoidf_fast(beta[g]);
    }

    // iter 2: out[f] = sum_g alpha2*con + bias[f]
    #pragma unroll
    for (int t = 0; t < 4; ++t)
        #pragma unroll
        for (int r = 0; r < 4; ++r) {
            int f = t * 16 + q * 4 + r;
            float s = bias[f];
            #pragma unroll
            for (int g = 0; g < NG; ++g) s += alpha[g] * acc[g][t][r];
            out[((size_t)(b * NFO + f)) * HW + p0 + pw] = s;
        }
}

extern "C" void kernel_launch(void* const* d_in, const int* in_sizes, int n_in,
                              void* d_out, int out_size, void* d_ws, size_t ws_size,
                              hipStream_t stream) {
    const float* x    = (const float*)d_in[0];
    const float* w    = (const float*)d_in[1];
    const float* bias = (const float*)d_in[2];
    float* out = (float*)d_out;
    _Float16* wbuf = (_Float16*)d_ws;   // 128 KiB fragment-ordered (h,l) weights

    wconv_kernel<<<32, 256, 0, stream>>>(w, wbuf);
    routing_kernel<<<1024, 256, 0, stream>>>(x, wbuf, bias, out);
}

// Round 3
// 201.160 us; speedup vs baseline: 1.0520x; 1.0011x over previous
//
#include <hip/hip_runtime.h>

// DynamicRouting: grouped 1x1 conv (einsum bgihw,gfi->bgfhw) + 3-iter routing.
// B=16, G=8, FI=FO=64, HW=4096. Fully fused: con never touches HBM.
//
// R7: single kernel. The separate wconv repack dispatch (~4-6 us of launch +
// stream-serialization bubble) is folded into routing_kernel: per group, each
// block loads the raw fp32 weight tile (L2-resident, 16 KB) into registers
// (4 x global_load_dwordx4 per wave - same FIFO slot WSTAGE used), converts
// to the fragment-ordered h/l fp16 split in VALU (hidden under the 5:1
// memory-bound slack), and ds_write_b128's it into wlds. vmcnt choreography
// identical to R6 (8 vmem instrs/wave/group, steady vmcnt(8), never 0
// mid-loop); added s_waitcnt lgkmcnt(0) before the pre-compute barrier so all
// waves' w-writes are visible (wave wv writes t=wv rows, all waves read all
// t). x path unchanged: global_load_lds width=16, rotation swizzle on the
// global source, conflict-free ds_read rebuild. Conversion arithmetic is
// bit-identical to the old wconv (h=cvt(f); l=cvt(f-(float)h)) -> absmax
// stays 0.125. Workspace unused.

typedef __attribute__((ext_vector_type(8))) _Float16 half8;
typedef __attribute__((ext_vector_type(4))) float f32x4;

#define NG   8
#define NFI  64
#define NFO  64
#define HW   4096

__device__ __forceinline__ float sigmoidf_fast(float v) {
    float e = __builtin_amdgcn_exp2f(-1.44269504088896f * v);
    return __builtin_amdgcn_rcpf(1.0f + e);
}

// ---- fused conv + routing: LDS-staged x AND w, depth-2 pipeline ----
__global__ __launch_bounds__(256, 2)
void routing_kernel(const float* __restrict__ x,
                    const float* __restrict__ w,
                    const float* __restrict__ bias,
                    float* __restrict__ out) {
    const int tid  = threadIdx.x;
    const int b    = blockIdx.x >> 6;          // batch
    const int p0   = (blockIdx.x & 63) << 6;   // pixel tile base
    const int lane = tid & 63;
    const int wv   = tid >> 6;                 // wave -> 16-px slice / w t-row
    const int pl   = lane & 15;                // MFMA n-lane (pixel)
    const int q    = lane >> 4;                // k-octet select / C row group
    const int pw   = wv * 16 + pl;             // pixel within tile

    // double-buffered tiles: x = 64ch x 64px fp32 (16 KB), w = 16 KB fp16
    __shared__ float    xlds[2][64 * 64];
    __shared__ _Float16 wlds[2][16 * 512];

    const float* xbase = x + (size_t)b * (NG * NFI) * HW;

    // w source for this thread's fragments: row t=wv*16+pl, k-octet q*8 (+32
    // for the upper k-half). Group g adds g*4096 floats. 16 B aligned.
    const float* wsrc = w + (size_t)(wv * 16 + pl) * NFI + q * 8;

    // per-lane X-stage source pointers. Stage instr c: wave writes LDS floats
    // [(wv*16 + c*4)*64, +256) linearly (lane i -> +i*4 floats). Lane covers
    // ch = wv*16 + c*4 + (lane>>4), slots pl*4..pl*4+3. Rotation swizzle:
    // LDS[ch*64 + s] holds pixel p = (s - 8*(ch>>3)) & 63, so the global
    // source is pre-rotated; runs of 4 slots map to contiguous 4-px runs.
#define MKXS(c) \
    const int   ch##c = wv * 16 + (c) * 4 + q; \
    const float* xs##c = xbase + (size_t)ch##c * HW + p0 + ((pl * 4 - 8 * (ch##c >> 3)) & 63);
    MKXS(0) MKXS(1) MKXS(2) MKXS(3)
#undef MKXS

    // b-frag read bases (floats, within a 16 KB x tile):
    //   b0 row ch=q*8+j  : rot=8q    -> slot=(pw+8q)&63,    + j*64
    //   b1 row ch=32+q*8+j: rot=32+8q -> slot=(pw+8q+32)&63, + j*64
    // bank = (pl + 8q + 16wv) mod 32 -> exactly 2 lanes/bank (free).
    const int rb0 = q * 512 + ((pw + 8 * q) & 63);
    const int rb1 = 2048 + q * 512 + ((pw + 8 * q + 32) & 63);

    f32x4 acc[NG][4];
    #pragma unroll
    for (int g = 0; g < NG; ++g)
        #pragma unroll
        for (int t = 0; t < 4; ++t)
            acc[g][t] = (f32x4){0.f, 0.f, 0.f, 0.f};

#define CB    asm volatile("" ::: "memory")
#define BAR   __builtin_amdgcn_s_barrier()
#define SB0   __builtin_amdgcn_sched_barrier(0)
#define WAITV(N) asm volatile("s_waitcnt vmcnt(" #N ")" ::: "memory")
#define LGKM0 asm volatile("s_waitcnt lgkmcnt(0)" ::: "memory")

    // load group G's raw fp32 weight octets for this thread (4 x dwordx4)
#define WLOAD(G, NM)                                                          \
    NM##a = *(const f32x4*)(wsrc + (size_t)(G) * 4096);                       \
    NM##b = *(const f32x4*)(wsrc + (size_t)(G) * 4096 + 4);                   \
    NM##c = *(const f32x4*)(wsrc + (size_t)(G) * 4096 + 32);                  \
    NM##d = *(const f32x4*)(wsrc + (size_t)(G) * 4096 + 36);

    // convert to h/l fp16 split (bit-identical to old wconv) and write the
    // fragment-ordered rows t=wv, c=0..3 into wlds[(G)&1]. Each ds_write_b128
    // has lanes at consecutive 16 B -> conflict-free.
#define WCONV(G, NM)                                                          \
    {                                                                         \
        half8 h0_, h1_, l0_, l1_;                                             \
        _Pragma("unroll")                                                     \
        for (int j = 0; j < 4; ++j) {                                         \
            float f0 = NM##a[j], f1 = NM##b[j], f2 = NM##c[j], f3 = NM##d[j]; \
            _Float16 e0 = (_Float16)f0, e1 = (_Float16)f1;                    \
            _Float16 e2 = (_Float16)f2, e3 = (_Float16)f3;                    \
            h0_[j] = e0; h0_[j + 4] = e1;                                     \
            h1_[j] = e2; h1_[j + 4] = e3;                                     \
            l0_[j]     = (_Float16)(f0 - (float)e0);                          \
            l0_[j + 4] = (_Float16)(f1 - (float)e1);                          \
            l1_[j]     = (_Float16)(f2 - (float)e2);                          \
            l1_[j + 4] = (_Float16)(f3 - (float)e3);                          \
        }                                                                     \
        _Float16* wd_ = &wlds[(G) & 1][0] + (wv * 4) * 512 + lane * 8;        \
        *(half8*)(wd_)        = h0_;                                          \
        *(half8*)(wd_ + 512)  = h1_;                                          \
        *(half8*)(wd_ + 1024) = l0_;                                          \
        *(half8*)(wd_ + 1536) = l1_;                                          \
    }

    // stage group G's 16 KB x tile: 4 x 1 KB global_load_lds per wave
#define XSTAGE(G, BUF)                                                        \
    {                                                                         \
        const size_t go_ = (size_t)(G) * 64 * HW;                             \
        float* xd_ = &xlds[BUF][0] + (wv * 16) * 64;                          \
        __builtin_amdgcn_global_load_lds(                                     \
            (const __attribute__((address_space(1))) void*)(xs0 + go_),       \
            (__attribute__((address_space(3))) void*)(xd_), 16, 0, 0);        \
        __builtin_amdgcn_global_load_lds(                                     \
            (const __attribute__((address_space(1))) void*)(xs1 + go_),       \
            (__attribute__((address_space(3))) void*)(xd_ + 256), 16, 0, 0);  \
        __builtin_amdgcn_global_load_lds(                                     \
            (const __attribute__((address_space(1))) void*)(xs2 + go_),       \
            (__attribute__((address_space(3))) void*)(xd_ + 512), 16, 0, 0);  \
        __builtin_amdgcn_global_load_lds(                                     \
            (const __attribute__((address_space(1))) void*)(xs3 + go_),       \
            (__attribute__((address_space(3))) void*)(xd_ + 768), 16, 0, 0);  \
    }

    // consume group G from buffer BUF: b-frags from xlds, a-frags from wlds
#define XGRP(G, BUF)                                                         \
    {                                                                        \
        const float* xr0_ = &xlds[BUF][0] + rb0;                             \
        const float* xr1_ = &xlds[BUF][0] + rb1;                             \
        half8 b0, b1;                                                        \
        b0[0] = (_Float16)xr0_[0 * 64]; b0[1] = (_Float16)xr0_[1 * 64];      \
        b0[2] = (_Float16)xr0_[2 * 64]; b0[3] = (_Float16)xr0_[3 * 64];      \
        b0[4] = (_Float16)xr0_[4 * 64]; b0[5] = (_Float16)xr0_[5 * 64];      \
        b0[6] = (_Float16)xr0_[6 * 64]; b0[7] = (_Float16)xr0_[7 * 64];      \
        b1[0] = (_Float16)xr1_[0 * 64]; b1[1] = (_Float16)xr1_[1 * 64];      \
        b1[2] = (_Float16)xr1_[2 * 64]; b1[3] = (_Float16)xr1_[3 * 64];      \
        b1[4] = (_Float16)xr1_[4 * 64]; b1[5] = (_Float16)xr1_[5 * 64];      \
        b1[6] = (_Float16)xr1_[6 * 64]; b1[7] = (_Float16)xr1_[7 * 64];      \
        const _Float16* wg_ = &wlds[BUF][0] + lane * 8;                      \
        _Pragma("unroll")                                                    \
        for (int t = 0; t < 4; ++t) {                                        \
            const _Float16* wp_ = wg_ + (size_t)t * 2048;                    \
            half8 a0h = *(const half8*)(wp_);                                \
            half8 a1h = *(const half8*)(wp_ + 512);                          \
            half8 a0l = *(const half8*)(wp_ + 1024);                         \
            half8 a1l = *(const half8*)(wp_ + 1536);                         \
            acc[G][t] = __builtin_amdgcn_mfma_f32_16x16x32_f16(a0h, b0, acc[G][t], 0, 0, 0); \
            acc[G][t] = __builtin_amdgcn_mfma_f32_16x16x32_f16(a1h, b1, acc[G][t], 0, 0, 0); \
            acc[G][t] = __builtin_amdgcn_mfma_f32_16x16x32_f16(a0l, b0, acc[G][t], 0, 0, 0); \
            acc[G][t] = __builtin_amdgcn_mfma_f32_16x16x32_f16(a1l, b1, acc[G][t], 0, 0, 0); \
        }                                                                    \
    }

    f32x4 Waa, Wab, Wac, Wad;   // w fp32 regs, even groups
    f32x4 Wba, Wbb, Wbc, Wbd;   // w fp32 regs, odd groups
#define Wa_a Waa
    // (names expanded via token pasting: Wa##a etc.)

    // Prologue FIFO: W0(4) X0(4) W1(4) X1(4)  -- 16 vmem instrs/wave in flight
    WLOAD(0, Wa) CB; XSTAGE(0, 0); CB;
    WLOAD(1, Wb) CB; XSTAGE(1, 1); CB;

    // Steady step g: [vmcnt(8): W(g) regs + X(g) LDS arrived, W(g+1)/X(g+1)
    // stay in flight] [convert+ds_write w(g)] [lgkmcnt(0): writes visible]
    // [barrier] [compute g] [barrier: bufs free] [issue W(g+2), X(g+2)].
    WAITV(8); WCONV(0, Wa) LGKM0; BAR; SB0; XGRP(0, 0); BAR; WLOAD(2, Wa) CB; XSTAGE(2, 0); CB;
    WAITV(8); WCONV(1, Wb) LGKM0; BAR; SB0; XGRP(1, 1); BAR; WLOAD(3, Wb) CB; XSTAGE(3, 1); CB;
    WAITV(8); WCONV(2, Wa) LGKM0; BAR; SB0; XGRP(2, 0); BAR; WLOAD(4, Wa) CB; XSTAGE(4, 0); CB;
    WAITV(8); WCONV(3, Wb) LGKM0; BAR; SB0; XGRP(3, 1); BAR; WLOAD(5, Wb) CB; XSTAGE(5, 1); CB;
    WAITV(8); WCONV(4, Wa) LGKM0; BAR; SB0; XGRP(4, 0); BAR; WLOAD(6, Wa) CB; XSTAGE(6, 0); CB;
    WAITV(8); WCONV(5, Wb) LGKM0; BAR; SB0; XGRP(5, 1); BAR; WLOAD(7, Wb) CB; XSTAGE(7, 1); CB;
    WAITV(8); WCONV(6, Wa) LGKM0; BAR; SB0; XGRP(6, 0); BAR;
    WAITV(0); WCONV(7, Wb) LGKM0; BAR; SB0; XGRP(7, 1);

#undef XGRP
#undef XSTAGE
#undef WCONV
#undef WLOAD
#undef CB
#undef BAR
#undef SB0
#undef WAITV
#undef LGKM0

    // ---- routing (all fp32, per pixel), f = t*16 + q*4 + r ----
    // iter 0: v0[f] = 0.5*sum_g con ; beta1[g] = sum_f v0*con
    float v0[4][4];
    #pragma unroll
    for (int t = 0; t < 4; ++t)
        #pragma unroll
        for (int r = 0; r < 4; ++r) {
            float s = 0.f;
            #pragma unroll
            for (int g = 0; g < NG; ++g) s += acc[g][t][r];
            v0[t][r] = 0.5f * s;
        }

    float beta[NG], alpha[NG];
    #pragma unroll
    for (int g = 0; g < NG; ++g) {
        float s = 0.f;
        #pragma unroll
        for (int t = 0; t < 4; ++t)
            #pragma unroll
            for (int r = 0; r < 4; ++r)
                s += v0[t][r] * acc[g][t][r];
        s += __shfl_xor(s, 16);   // close f-sum across the 4 q-lanes
        s += __shfl_xor(s, 32);
        beta[g]  = s;
        alpha[g] = sigmoidf_fast(s);
    }

    // iter 1: v1[f] = sum_g alpha*con ; beta2 = beta1 + sum_f v1*con
    #pragma unroll
    for (int t = 0; t < 4; ++t)
        #pragma unroll
        for (int r = 0; r < 4; ++r) {
            float s = 0.f;
            #pragma unroll
            for (int g = 0; g < NG; ++g) s += alpha[g] * acc[g][t][r];
            v0[t][r] = s;  // reuse as v1
        }
    #pragma unroll
    for (int g = 0; g < NG; ++g) {
        float s = 0.f;
        #pragma unroll
        for (int t = 0; t < 4; ++t)
            #pragma unroll
            for (int r = 0; r < 4; ++r)
                s += v0[t][r] * acc[g][t][r];
        s += __shfl_xor(s, 16);
        s += __shfl_xor(s, 32);
        beta[g] += s;
        alpha[g] = sigmoidf_fast(beta[g]);
    }

    // iter 2: out[f] = sum_g alpha2*con + bias[f]
    #pragma unroll
    for (int t = 0; t < 4; ++t)
        #pragma unroll
        for (int r = 0; r < 4; ++r) {
            int f = t * 16 + q * 4 + r;
            float s = bias[f];
            #pragma unroll
            for (int g = 0; g < NG; ++g) s += alpha[g] * acc[g][t][r];
            out[((size_t)(b * NFO + f)) * HW + p0 + pw] = s;
        }
}

extern "C" void kernel_launch(void* const* d_in, const int* in_sizes, int n_in,
                              void* d_out, int out_size, void* d_ws, size_t ws_size,
                              hipStream_t stream) {
    const float* x    = (const float*)d_in[0];
    const float* w    = (const float*)d_in[1];
    const float* bias = (const float*)d_in[2];
    float* out = (float*)d_out;
    (void)d_ws; (void)ws_size;   // workspace no longer used

    routing_kernel<<<1024, 256, 0, stream>>>(x, w, bias, out);
}